// Round 1
// baseline (1672.185 us; speedup 1.0000x reference)
//
#include <hip/hip_runtime.h>
#include <hip/hip_bf16.h>

// ConvMultiStepAttention: B=16, C=T=S=1024, fp32.
//   preatt[b,d,t] = sum_c W[d,c] x[b,c,t] + bias[d]
//   tgt[b,t,d]    = (base[b,d,t] + preatt) * sqrt(0.5)        (ws, [B,T,C])
//   scores[b,t,s] = sum_c tgt[b,t,c] top[b,c,s]               (-> attn region)
//   attn          = softmax_S(scores)                          (in place)
//   ctx[b,c,t]    = sum_s comb[b,c,s] attn[b,t,s]             (-> context region)
//
// Round 0: fp32 vector baseline (no fp32 MFMA on CDNA4). 64x64 tiles, BK=32,
// 256 thr, 4x4 acc/thread. Compute-side LDS reads are b128 conflict-free;
// transpose-scatter stores (8-way) are amortized (8 ds_write_b32 vs 1024
// FMA-cyc per K-chunk).

#define SCALE_W 0.70710678118654752440f

constexpr int Bb = 16, Cc = 1024, Tt = 1024, Ss = 1024;

// ---------------------------------------------------------------------------
// GEMM1: tgt[b][t][d] = SCALE*(base[b][d][t] + bias[d] + sum_c W[d][c]*x[b][c][t])
// m=t, n=d, k=c.  A = x[b] ([k][m], m contig -> direct stage).
//                 B = W    ([n][k], k contig -> transpose-scatter stage).
// ---------------------------------------------------------------------------
__global__ __launch_bounds__(256) void gemm1_kernel(
    const float* __restrict__ x, const float* __restrict__ W,
    const float* __restrict__ base, const float* __restrict__ bias,
    float* __restrict__ tgt) {
  __shared__ float as_[32][64];  // [k][m]
  __shared__ float bs_[32][64];  // [k][n]
  const int b = blockIdx.z;
  const int m0 = blockIdx.y * 64;  // t
  const int n0 = blockIdx.x * 64;  // d
  const int tid = threadIdx.x;
  const int tx = tid & 15, ty = tid >> 4;

  const float* xb = x + (size_t)b * Cc * Tt;
  float acc[4][4] = {};

  for (int k0 = 0; k0 < Cc; k0 += 32) {
#pragma unroll
    for (int r = 0; r < 2; ++r) {
      int f = tid + r * 256;
      // A: as_[kk][mm] = x[b][k0+kk][m0+mm]   (m contiguous, direct float4)
      int kk = f >> 4, mq = f & 15;
      float4 v = *(const float4*)(xb + (size_t)(k0 + kk) * Tt + m0 + mq * 4);
      *(float4*)(&as_[kk][mq * 4]) = v;
      // B: bs_[kk][nn] = W[n0+nn][k0+kk]      (k contiguous, scatter)
      int nn = f >> 3, kq = f & 7;
      float4 w = *(const float4*)(W + (size_t)(n0 + nn) * Cc + k0 + kq * 4);
      bs_[kq * 4 + 0][nn] = w.x;
      bs_[kq * 4 + 1][nn] = w.y;
      bs_[kq * 4 + 2][nn] = w.z;
      bs_[kq * 4 + 3][nn] = w.w;
    }
    __syncthreads();
#pragma unroll
    for (int kk = 0; kk < 32; ++kk) {
      float4 av = *(const float4*)(&as_[kk][ty * 4]);
      float4 bv = *(const float4*)(&bs_[kk][tx * 4]);
      float a[4] = {av.x, av.y, av.z, av.w};
      float bb[4] = {bv.x, bv.y, bv.z, bv.w};
#pragma unroll
      for (int i = 0; i < 4; ++i)
#pragma unroll
        for (int j = 0; j < 4; ++j) acc[i][j] = fmaf(a[i], bb[j], acc[i][j]);
    }
    __syncthreads();
  }

  // Epilogue: + bias + base (base is [d][t]: float4 over t per output col)
  const float* baseb = base + (size_t)b * Cc * Tt;
  float* out = tgt + (size_t)b * Tt * Cc;
  float res[4][4];
#pragma unroll
  for (int j = 0; j < 4; ++j) {
    int d = n0 + tx * 4 + j;
    float bd = bias[d];
    float4 bv = *(const float4*)(baseb + (size_t)d * Tt + m0 + ty * 4);
    res[0][j] = (acc[0][j] + bd + bv.x) * SCALE_W;
    res[1][j] = (acc[1][j] + bd + bv.y) * SCALE_W;
    res[2][j] = (acc[2][j] + bd + bv.z) * SCALE_W;
    res[3][j] = (acc[3][j] + bd + bv.w) * SCALE_W;
  }
#pragma unroll
  for (int i = 0; i < 4; ++i) {
    int t = m0 + ty * 4 + i;
    float4 o = {res[i][0], res[i][1], res[i][2], res[i][3]};
    *(float4*)(out + (size_t)t * Cc + n0 + tx * 4) = o;
  }
}

// ---------------------------------------------------------------------------
// GEMM2: scores[b][t][s] = sum_c tgt[b][t][c] * top[b][c][s]
// m=t, n=s, k=c.  A = tgt[b] ([m][k], k contig -> scatter).
//                 B = top[b] ([k][n], n contig -> direct).
// ---------------------------------------------------------------------------
__global__ __launch_bounds__(256) void gemm2_kernel(
    const float* __restrict__ tgt, const float* __restrict__ top,
    float* __restrict__ scores) {
  __shared__ float as_[32][64];
  __shared__ float bs_[32][64];
  const int b = blockIdx.z;
  const int m0 = blockIdx.y * 64;  // t
  const int n0 = blockIdx.x * 64;  // s
  const int tid = threadIdx.x;
  const int tx = tid & 15, ty = tid >> 4;

  const float* ab = tgt + (size_t)b * Tt * Cc;
  const float* bbp = top + (size_t)b * Cc * Ss;
  float acc[4][4] = {};

  for (int k0 = 0; k0 < Cc; k0 += 32) {
#pragma unroll
    for (int r = 0; r < 2; ++r) {
      int f = tid + r * 256;
      int mm = f >> 3, kq = f & 7;
      float4 a = *(const float4*)(ab + (size_t)(m0 + mm) * Cc + k0 + kq * 4);
      as_[kq * 4 + 0][mm] = a.x;
      as_[kq * 4 + 1][mm] = a.y;
      as_[kq * 4 + 2][mm] = a.z;
      as_[kq * 4 + 3][mm] = a.w;
      int kk = f >> 4, nq = f & 15;
      float4 v = *(const float4*)(bbp + (size_t)(k0 + kk) * Ss + n0 + nq * 4);
      *(float4*)(&bs_[kk][nq * 4]) = v;
    }
    __syncthreads();
#pragma unroll
    for (int kk = 0; kk < 32; ++kk) {
      float4 av = *(const float4*)(&as_[kk][ty * 4]);
      float4 bv = *(const float4*)(&bs_[kk][tx * 4]);
      float a[4] = {av.x, av.y, av.z, av.w};
      float bb[4] = {bv.x, bv.y, bv.z, bv.w};
#pragma unroll
      for (int i = 0; i < 4; ++i)
#pragma unroll
        for (int j = 0; j < 4; ++j) acc[i][j] = fmaf(a[i], bb[j], acc[i][j]);
    }
    __syncthreads();
  }

  float* out = scores + (size_t)b * Tt * Ss;
#pragma unroll
  for (int i = 0; i < 4; ++i) {
    int t = m0 + ty * 4 + i;
    float4 o = {acc[i][0], acc[i][1], acc[i][2], acc[i][3]};
    *(float4*)(out + (size_t)t * Ss + n0 + tx * 4) = o;
  }
}

// ---------------------------------------------------------------------------
// Softmax over S=1024, one block (256 thr) per row, in place.
// ---------------------------------------------------------------------------
__global__ __launch_bounds__(256) void softmax_kernel(float* __restrict__ attn) {
  __shared__ float red[8];
  float* p = attn + (size_t)blockIdx.x * Ss;
  const int tid = threadIdx.x;
  float4 v = *(float4*)(p + tid * 4);
  float m = fmaxf(fmaxf(v.x, v.y), fmaxf(v.z, v.w));
#pragma unroll
  for (int off = 1; off < 64; off <<= 1) m = fmaxf(m, __shfl_xor(m, off));
  const int wave = tid >> 6, lane = tid & 63;
  if (lane == 0) red[wave] = m;
  __syncthreads();
  m = fmaxf(fmaxf(red[0], red[1]), fmaxf(red[2], red[3]));
  v.x = __expf(v.x - m);
  v.y = __expf(v.y - m);
  v.z = __expf(v.z - m);
  v.w = __expf(v.w - m);
  float s = v.x + v.y + v.z + v.w;
#pragma unroll
  for (int off = 1; off < 64; off <<= 1) s += __shfl_xor(s, off);
  if (lane == 0) red[4 + wave] = s;
  __syncthreads();
  s = red[4] + red[5] + red[6] + red[7];
  float inv = 1.0f / s;
  v.x *= inv;
  v.y *= inv;
  v.z *= inv;
  v.w *= inv;
  *(float4*)(p + tid * 4) = v;
}

// ---------------------------------------------------------------------------
// GEMM3: ctx[b][c][t] = sum_s comb[b][c][s] * attn[b][t][s]
// m=c, n=t, k=s.  A = comb[b] ([m][k], k contig -> scatter).
//                 B = attn[b] ([n][k], k contig -> scatter).
// ---------------------------------------------------------------------------
__global__ __launch_bounds__(256) void gemm3_kernel(
    const float* __restrict__ comb, const float* __restrict__ attn,
    float* __restrict__ ctx) {
  __shared__ float as_[32][64];
  __shared__ float bs_[32][64];
  const int b = blockIdx.z;
  const int m0 = blockIdx.y * 64;  // c
  const int n0 = blockIdx.x * 64;  // t
  const int tid = threadIdx.x;
  const int tx = tid & 15, ty = tid >> 4;

  const float* ab = comb + (size_t)b * Cc * Ss;
  const float* bbp = attn + (size_t)b * Tt * Ss;
  float acc[4][4] = {};

  for (int k0 = 0; k0 < Ss; k0 += 32) {
#pragma unroll
    for (int r = 0; r < 2; ++r) {
      int f = tid + r * 256;
      int rr = f >> 3, kq = f & 7;
      float4 a = *(const float4*)(ab + (size_t)(m0 + rr) * Ss + k0 + kq * 4);
      as_[kq * 4 + 0][rr] = a.x;
      as_[kq * 4 + 1][rr] = a.y;
      as_[kq * 4 + 2][rr] = a.z;
      as_[kq * 4 + 3][rr] = a.w;
      float4 bv = *(const float4*)(bbp + (size_t)(n0 + rr) * Ss + k0 + kq * 4);
      bs_[kq * 4 + 0][rr] = bv.x;
      bs_[kq * 4 + 1][rr] = bv.y;
      bs_[kq * 4 + 2][rr] = bv.z;
      bs_[kq * 4 + 3][rr] = bv.w;
    }
    __syncthreads();
#pragma unroll
    for (int kk = 0; kk < 32; ++kk) {
      float4 av = *(const float4*)(&as_[kk][ty * 4]);
      float4 bv = *(const float4*)(&bs_[kk][tx * 4]);
      float a[4] = {av.x, av.y, av.z, av.w};
      float bb[4] = {bv.x, bv.y, bv.z, bv.w};
#pragma unroll
      for (int i = 0; i < 4; ++i)
#pragma unroll
        for (int j = 0; j < 4; ++j) acc[i][j] = fmaf(a[i], bb[j], acc[i][j]);
    }
    __syncthreads();
  }

  float* out = ctx + (size_t)b * Cc * Tt;
#pragma unroll
  for (int i = 0; i < 4; ++i) {
    int c = m0 + ty * 4 + i;
    float4 o = {acc[i][0], acc[i][1], acc[i][2], acc[i][3]};
    *(float4*)(out + (size_t)c * Tt + n0 + tx * 4) = o;
  }
}

extern "C" void kernel_launch(void* const* d_in, const int* in_sizes, int n_in,
                              void* d_out, int out_size, void* d_ws,
                              size_t ws_size, hipStream_t stream) {
  const float* base = (const float*)d_in[0];  // [B,C,T]
  const float* x = (const float*)d_in[1];     // [B,C,T]
  const float* top = (const float*)d_in[2];   // [B,C,S]
  const float* comb = (const float*)d_in[3];  // [B,C,S]
  const float* W = (const float*)d_in[4];     // [C,C]
  const float* bias = (const float*)d_in[5];  // [C]

  float* ctx_out = (float*)d_out;                        // [B,C,T]
  float* attn = (float*)d_out + (size_t)Bb * Cc * Tt;    // [B,T,S]
  float* tgt = (float*)d_ws;                             // [B,T,C] (64 MB)

  dim3 blk(256);
  gemm1_kernel<<<dim3(Cc / 64, Tt / 64, Bb), blk, 0, stream>>>(x, W, base, bias, tgt);
  gemm2_kernel<<<dim3(Ss / 64, Tt / 64, Bb), blk, 0, stream>>>(tgt, top, attn);
  softmax_kernel<<<dim3(Bb * Tt), blk, 0, stream>>>(attn);
  gemm3_kernel<<<dim3(Tt / 64, Cc / 64, Bb), blk, 0, stream>>>(comb, attn, ctx_out);
}

// Round 2
// 718.973 us; speedup vs baseline: 2.3258x; 2.3258x over previous
//
#include <hip/hip_runtime.h>

// ConvMultiStepAttention, B=16, C=T=S=1024, fp32 in/out.
// R2: bf16 MFMA (16x16x32) with hi/lo split-precision on the score path.
//   scores sigma=32 -> softmax near-one-hot -> need ~fp32 logits.
//   tgt = GEMM1(W,x)+base+bias: W,x split hi/lo (3-product MFMA) -> tgt
//   stored as hi/lo bf16 planes. scores = GEMM2(tgt_hi/lo, top_hi/lo)
//   (3-product). GEMM3(attn, comb) plain bf16 (insensitive).
// Buffer plan (no extra allocs):
//   d_ws  [64MB]: tgtH | tgtL            (bf16 [B][T][C] planes)
//   d_out ctx region [64MB]: topH | topL  (dead once gemm3 writes ctx)
//   d_out attn region [64MB]: xtH | xtL   (dead once gemm2 writes scores)

typedef float  floatx4 __attribute__((ext_vector_type(4)));
typedef short  short8  __attribute__((ext_vector_type(8)));
typedef short  short4v __attribute__((ext_vector_type(4)));
typedef __bf16 bf16x8  __attribute__((ext_vector_type(8)));

constexpr int Bb = 16, Cc = 1024, Tt = 1024, Ss = 1024;
#define SCALE_W 0.70710678118654752440f

__device__ __forceinline__ floatx4 mfma16(short8 a, short8 b, floatx4 c) {
  return __builtin_amdgcn_mfma_f32_16x16x32_bf16(
      __builtin_bit_cast(bf16x8, a), __builtin_bit_cast(bf16x8, b), c, 0, 0, 0);
}
__device__ __forceinline__ unsigned short f2bf(float f) {  // RNE
  unsigned u = __builtin_bit_cast(unsigned, f);
  u += 0x7fff + ((u >> 16) & 1);
  return (unsigned short)(u >> 16);
}
__device__ __forceinline__ float bf2f(unsigned short h) {
  return __builtin_bit_cast(float, (unsigned)h << 16);
}
#define GLDS16(g, l)                                        \
  __builtin_amdgcn_global_load_lds(                         \
      (const __attribute__((address_space(1))) void*)(g),   \
      (__attribute__((address_space(3))) void*)(l), 16, 0, 0)

// ---------------------------------------------------------------------------
// Transpose + hi/lo split: in[b][i][j] fp32 -> outH/outL[b][j][i] bf16.
// ---------------------------------------------------------------------------
__global__ __launch_bounds__(256) void transpose_split_kernel(
    const float* __restrict__ in, unsigned short* __restrict__ outH,
    unsigned short* __restrict__ outL) {
  __shared__ float tile[64][65];
  const int b = blockIdx.z;
  const int i0 = blockIdx.y * 64;
  const int j0 = blockIdx.x * 64;
  const int tid = threadIdx.x;
  const float* pin = in + ((size_t)b * 1024 + i0) * 1024 + j0;
#pragma unroll
  for (int it = 0; it < 4; ++it) {
    int e = tid + it * 256;
    int r = e >> 4, ch = e & 15;
    float4 v = *(const float4*)(pin + (size_t)r * 1024 + ch * 4);
    tile[r][ch * 4 + 0] = v.x;
    tile[r][ch * 4 + 1] = v.y;
    tile[r][ch * 4 + 2] = v.z;
    tile[r][ch * 4 + 3] = v.w;
  }
  __syncthreads();
#pragma unroll
  for (int it = 0; it < 4; ++it) {
    int e = tid + it * 256;
    int r = e >> 4, ch = e & 15;  // r: out row (j), ch: out col chunk (i)
    short4v h, lo;
#pragma unroll
    for (int q = 0; q < 4; ++q) {
      float f = tile[ch * 4 + q][r];
      unsigned short hh = f2bf(f);
      h[q] = (short)hh;
      lo[q] = (short)f2bf(f - bf2f(hh));
    }
    size_t o = ((size_t)b * 1024 + j0 + r) * 1024 + i0 + ch * 4;
    *(short4v*)(outH + o) = h;
    *(short4v*)(outL + o) = lo;
  }
}

// ---------------------------------------------------------------------------
// GEMM1 (split x split): tgt[t][d] = SCALE*(base[d][t]+bias[d]+sum_c W[d][c]x[c][t])
// MFMA view: m=d, n=t, k=c.  A=W [m][k] fp32 (VGPR-split staging).
// B=xt [n=t][k=c] bf16 hi/lo (glds).  Epilogue emits tgt hi/lo planes [t][c].
// ---------------------------------------------------------------------------
__global__ __launch_bounds__(256) void gemm1_kernel(
    const float* __restrict__ W, const unsigned short* __restrict__ xH,
    const unsigned short* __restrict__ xL, const float* __restrict__ base,
    const float* __restrict__ bias, unsigned short* __restrict__ tgtH,
    unsigned short* __restrict__ tgtL) {
  __shared__ alignas(16) short AsH[128 * 32], AsL[128 * 32];
  __shared__ alignas(16) short BsH[128 * 32], BsL[128 * 32];
  const int b = blockIdx.z;
  const int m0 = blockIdx.y * 128;  // d
  const int n0 = blockIdx.x * 128;  // t
  const int tid = threadIdx.x;
  const int wid = tid >> 6, l = tid & 63;
  const int wm = (wid >> 1) * 64, wn = (wid & 1) * 64;
  const int quad = l >> 4, l15 = l & 15;

  floatx4 acc[4][4];
#pragma unroll
  for (int i = 0; i < 4; ++i)
#pragma unroll
    for (int j = 0; j < 4; ++j) acc[i][j] = (floatx4){0.f, 0.f, 0.f, 0.f};

  const size_t xoff = ((size_t)b * Tt + n0) * Cc;
  const int rb0 = wid * 32, rb1 = wid * 32 + 16;
  const int lrow = l >> 2, lcol = (l & 3) * 8;

  for (int k0 = 0; k0 < Cc; k0 += 32) {
    // A: W fp32 -> hi/lo bf16 in LDS [m][k]
#pragma unroll
    for (int it = 0; it < 4; ++it) {
      int e = tid + it * 256;
      int row = e >> 3, ch = e & 7;
      float4 w = *(const float4*)(W + (size_t)(m0 + row) * Cc + k0 + ch * 4);
      float wv[4] = {w.x, w.y, w.z, w.w};
      short4v h, lo;
#pragma unroll
      for (int q = 0; q < 4; ++q) {
        unsigned short hh = f2bf(wv[q]);
        h[q] = (short)hh;
        lo[q] = (short)f2bf(wv[q] - bf2f(hh));
      }
      *(short4v*)&AsH[row * 32 + ch * 4] = h;
      *(short4v*)&AsL[row * 32 + ch * 4] = lo;
    }
    // B: xt hi/lo via global_load_lds (16B/lane)
    GLDS16(xH + xoff + (size_t)(rb0 + lrow) * Cc + k0 + lcol, &BsH[rb0 * 32]);
    GLDS16(xH + xoff + (size_t)(rb1 + lrow) * Cc + k0 + lcol, &BsH[rb1 * 32]);
    GLDS16(xL + xoff + (size_t)(rb0 + lrow) * Cc + k0 + lcol, &BsL[rb0 * 32]);
    GLDS16(xL + xoff + (size_t)(rb1 + lrow) * Cc + k0 + lcol, &BsL[rb1 * 32]);
    __syncthreads();
    short8 aH[4], aL[4], bH[4], bL[4];
#pragma unroll
    for (int i = 0; i < 4; ++i) {
      aH[i] = *(const short8*)&AsH[(wm + i * 16 + l15) * 32 + quad * 8];
      aL[i] = *(const short8*)&AsL[(wm + i * 16 + l15) * 32 + quad * 8];
      bH[i] = *(const short8*)&BsH[(wn + i * 16 + l15) * 32 + quad * 8];
      bL[i] = *(const short8*)&BsL[(wn + i * 16 + l15) * 32 + quad * 8];
    }
#pragma unroll
    for (int i = 0; i < 4; ++i)
#pragma unroll
      for (int j = 0; j < 4; ++j) {
        acc[i][j] = mfma16(aH[i], bH[j], acc[i][j]);
        acc[i][j] = mfma16(aH[i], bL[j], acc[i][j]);
        acc[i][j] = mfma16(aL[i], bH[j], acc[i][j]);
      }
    __syncthreads();
  }
  // Epilogue: + bias + base, scale, split hi/lo, store [t][c]
#pragma unroll
  for (int i = 0; i < 4; ++i) {
    int dbase = m0 + wm + i * 16 + quad * 4;
    float4 bv = *(const float4*)(bias + dbase);
    float bvv[4] = {bv.x, bv.y, bv.z, bv.w};
#pragma unroll
    for (int j = 0; j < 4; ++j) {
      int t = n0 + wn + j * 16 + l15;
      short4v h, lo;
#pragma unroll
      for (int r = 0; r < 4; ++r) {
        float v = (acc[i][j][r] + bvv[r] +
                   base[((size_t)b * Cc + dbase + r) * Tt + t]) * SCALE_W;
        unsigned short hh = f2bf(v);
        h[r] = (short)hh;
        lo[r] = (short)f2bf(v - bf2f(hh));
      }
      size_t o = ((size_t)b * Tt + t) * Cc + dbase;
      *(short4v*)(tgtH + o) = h;
      *(short4v*)(tgtL + o) = lo;
    }
  }
}

// ---------------------------------------------------------------------------
// GEMM2 (split x split): scores[t][s] = sum_c tgt[t][c] top_t[s][c]
// m=t, n=s, k=c.  A=tgt hi/lo [t][c] glds; B=top_t hi/lo [s][c] glds.
// ---------------------------------------------------------------------------
__global__ __launch_bounds__(256) void gemm2_kernel(
    const unsigned short* __restrict__ tgtH, const unsigned short* __restrict__ tgtL,
    const unsigned short* __restrict__ topH, const unsigned short* __restrict__ topL,
    float* __restrict__ scores) {
  __shared__ alignas(16) short AsH[128 * 32], AsL[128 * 32];
  __shared__ alignas(16) short BsH[128 * 32], BsL[128 * 32];
  const int b = blockIdx.z;
  const int t0 = blockIdx.y * 128;  // m
  const int s0 = blockIdx.x * 128;  // n
  const int tid = threadIdx.x;
  const int wid = tid >> 6, l = tid & 63;
  const int wm = (wid >> 1) * 64, wn = (wid & 1) * 64;
  const int quad = l >> 4, l15 = l & 15;

  floatx4 acc[4][4];
#pragma unroll
  for (int i = 0; i < 4; ++i)
#pragma unroll
    for (int j = 0; j < 4; ++j) acc[i][j] = (floatx4){0.f, 0.f, 0.f, 0.f};

  const size_t aoff = ((size_t)b * Tt + t0) * Cc;
  const size_t boff = ((size_t)b * Ss + s0) * Cc;
  const int rb0 = wid * 32, rb1 = wid * 32 + 16;
  const int lrow = l >> 2, lcol = (l & 3) * 8;

  for (int k0 = 0; k0 < Cc; k0 += 32) {
    GLDS16(tgtH + aoff + (size_t)(rb0 + lrow) * Cc + k0 + lcol, &AsH[rb0 * 32]);
    GLDS16(tgtH + aoff + (size_t)(rb1 + lrow) * Cc + k0 + lcol, &AsH[rb1 * 32]);
    GLDS16(tgtL + aoff + (size_t)(rb0 + lrow) * Cc + k0 + lcol, &AsL[rb0 * 32]);
    GLDS16(tgtL + aoff + (size_t)(rb1 + lrow) * Cc + k0 + lcol, &AsL[rb1 * 32]);
    GLDS16(topH + boff + (size_t)(rb0 + lrow) * Cc + k0 + lcol, &BsH[rb0 * 32]);
    GLDS16(topH + boff + (size_t)(rb1 + lrow) * Cc + k0 + lcol, &BsH[rb1 * 32]);
    GLDS16(topL + boff + (size_t)(rb0 + lrow) * Cc + k0 + lcol, &BsL[rb0 * 32]);
    GLDS16(topL + boff + (size_t)(rb1 + lrow) * Cc + k0 + lcol, &BsL[rb1 * 32]);
    __syncthreads();
    short8 aH[4], aL[4], bH[4], bL[4];
#pragma unroll
    for (int i = 0; i < 4; ++i) {
      aH[i] = *(const short8*)&AsH[(wm + i * 16 + l15) * 32 + quad * 8];
      aL[i] = *(const short8*)&AsL[(wm + i * 16 + l15) * 32 + quad * 8];
      bH[i] = *(const short8*)&BsH[(wn + i * 16 + l15) * 32 + quad * 8];
      bL[i] = *(const short8*)&BsL[(wn + i * 16 + l15) * 32 + quad * 8];
    }
#pragma unroll
    for (int i = 0; i < 4; ++i)
#pragma unroll
      for (int j = 0; j < 4; ++j) {
        acc[i][j] = mfma16(aH[i], bH[j], acc[i][j]);
        acc[i][j] = mfma16(aH[i], bL[j], acc[i][j]);
        acc[i][j] = mfma16(aL[i], bH[j], acc[i][j]);
      }
    __syncthreads();
  }
#pragma unroll
  for (int i = 0; i < 4; ++i)
#pragma unroll
    for (int j = 0; j < 4; ++j) {
      int s_ = s0 + wn + j * 16 + l15;
#pragma unroll
      for (int r = 0; r < 4; ++r) {
        int t_ = t0 + wm + i * 16 + quad * 4 + r;
        scores[((size_t)b * Tt + t_) * Ss + s_] = acc[i][j][r];
      }
    }
}

// ---------------------------------------------------------------------------
// Softmax over S=1024, one block per row, in place (fp32).
// ---------------------------------------------------------------------------
__global__ __launch_bounds__(256) void softmax_kernel(float* __restrict__ attn) {
  __shared__ float red[8];
  float* p = attn + (size_t)blockIdx.x * Ss;
  const int tid = threadIdx.x;
  float4 v = *(float4*)(p + tid * 4);
  float m = fmaxf(fmaxf(v.x, v.y), fmaxf(v.z, v.w));
#pragma unroll
  for (int off = 1; off < 64; off <<= 1) m = fmaxf(m, __shfl_xor(m, off));
  const int wave = tid >> 6, lane = tid & 63;
  if (lane == 0) red[wave] = m;
  __syncthreads();
  m = fmaxf(fmaxf(red[0], red[1]), fmaxf(red[2], red[3]));
  v.x = __expf(v.x - m);
  v.y = __expf(v.y - m);
  v.z = __expf(v.z - m);
  v.w = __expf(v.w - m);
  float s = v.x + v.y + v.z + v.w;
#pragma unroll
  for (int off = 1; off < 64; off <<= 1) s += __shfl_xor(s, off);
  if (lane == 0) red[4 + wave] = s;
  __syncthreads();
  s = red[4] + red[5] + red[6] + red[7];
  float inv = 1.0f / s;
  v.x *= inv;
  v.y *= inv;
  v.z *= inv;
  v.w *= inv;
  *(float4*)(p + tid * 4) = v;
}

// ---------------------------------------------------------------------------
// GEMM3 (plain bf16): ctx[c][t] = sum_s comb[c][s] attn[t][s]
// m=c, n=t, k=s.  A=comb [c][s] fp32->bf16; B=attn [t][s] fp32->bf16.
// ---------------------------------------------------------------------------
__global__ __launch_bounds__(256) void gemm3_kernel(
    const float* __restrict__ comb, const float* __restrict__ attn,
    float* __restrict__ ctx) {
  __shared__ alignas(16) short As[128 * 32], Bs[128 * 32];
  const int b = blockIdx.z;
  const int m0 = blockIdx.y * 128;  // c
  const int n0 = blockIdx.x * 128;  // t
  const int tid = threadIdx.x;
  const int wid = tid >> 6, l = tid & 63;
  const int wm = (wid >> 1) * 64, wn = (wid & 1) * 64;
  const int quad = l >> 4, l15 = l & 15;

  floatx4 acc[4][4];
#pragma unroll
  for (int i = 0; i < 4; ++i)
#pragma unroll
    for (int j = 0; j < 4; ++j) acc[i][j] = (floatx4){0.f, 0.f, 0.f, 0.f};

  const float* pa = comb + ((size_t)b * Cc + m0) * Ss;
  const float* pb = attn + ((size_t)b * Tt + n0) * Ss;

  for (int k0 = 0; k0 < Ss; k0 += 32) {
#pragma unroll
    for (int it = 0; it < 4; ++it) {
      int e = tid + it * 256;
      int row = e >> 3, ch = e & 7;
      float4 a = *(const float4*)(pa + (size_t)row * Ss + k0 + ch * 4);
      float4 bb = *(const float4*)(pb + (size_t)row * Ss + k0 + ch * 4);
      short4v av, bv;
      float af[4] = {a.x, a.y, a.z, a.w};
      float bf[4] = {bb.x, bb.y, bb.z, bb.w};
#pragma unroll
      for (int q = 0; q < 4; ++q) {
        av[q] = (short)f2bf(af[q]);
        bv[q] = (short)f2bf(bf[q]);
      }
      *(short4v*)&As[row * 32 + ch * 4] = av;
      *(short4v*)&Bs[row * 32 + ch * 4] = bv;
    }
    __syncthreads();
    short8 af[4], bf[4];
#pragma unroll
    for (int i = 0; i < 4; ++i) {
      af[i] = *(const short8*)&As[(wm + i * 16 + l15) * 32 + quad * 8];
      bf[i] = *(const short8*)&Bs[(wn + i * 16 + l15) * 32 + quad * 8];
    }
#pragma unroll
    for (int i = 0; i < 4; ++i)
#pragma unroll
      for (int j = 0; j < 4; ++j) acc[i][j] = mfma16(af[i], bf[j], acc[i][j]);
    __syncthreads();
  }
#pragma unroll
  for (int i = 0; i < 4; ++i)
#pragma unroll
    for (int j = 0; j < 4; ++j) {
      int t_ = n0 + wn + j * 16 + l15;
#pragma unroll
      for (int r = 0; r < 4; ++r) {
        int c_ = m0 + wm + i * 16 + quad * 4 + r;
        ctx[((size_t)b * Cc + c_) * Tt + t_] = acc[i][j][r];
      }
    }
}

extern "C" void kernel_launch(void* const* d_in, const int* in_sizes, int n_in,
                              void* d_out, int out_size, void* d_ws,
                              size_t ws_size, hipStream_t stream) {
  const float* base = (const float*)d_in[0];  // [B,C,T]
  const float* x = (const float*)d_in[1];     // [B,C,T]
  const float* top = (const float*)d_in[2];   // [B,C,S]
  const float* comb = (const float*)d_in[3];  // [B,C,S]
  const float* W = (const float*)d_in[4];     // [C,C]
  const float* bias = (const float*)d_in[5];  // [C]

  const size_t NE = (size_t)Bb * 1024 * 1024;  // 16M elements per plane
  float* ctx_out = (float*)d_out;              // [B,C,T]
  float* attn = (float*)d_out + NE;            // [B,T,S]
  // temp planes in dead output regions:
  unsigned short* topH = (unsigned short*)d_out;  // ctx region, dead until gemm3
  unsigned short* topL = topH + NE;
  unsigned short* xtH = (unsigned short*)attn;  // attn region, dead until gemm2
  unsigned short* xtL = xtH + NE;
  unsigned short* tgtH = (unsigned short*)d_ws;  // ws: 64 MB
  unsigned short* tgtL = tgtH + NE;

  dim3 blk(256);
  transpose_split_kernel<<<dim3(16, 16, Bb), blk, 0, stream>>>(x, xtH, xtL);
  transpose_split_kernel<<<dim3(16, 16, Bb), blk, 0, stream>>>(top, topH, topL);
  gemm1_kernel<<<dim3(Tt / 128, Cc / 128, Bb), blk, 0, stream>>>(
      W, xtH, xtL, base, bias, tgtH, tgtL);
  gemm2_kernel<<<dim3(Ss / 128, Tt / 128, Bb), blk, 0, stream>>>(
      tgtH, tgtL, topH, topL, attn);
  softmax_kernel<<<dim3(Bb * Tt), blk, 0, stream>>>(attn);
  gemm3_kernel<<<dim3(Tt / 128, Cc / 128, Bb), blk, 0, stream>>>(comb, attn, ctx_out);
}